// Round 10
// baseline (268.917 us; speedup 1.0000x reference)
//
#include <hip/hip_runtime.h>
#include <math.h>

constexpr int Bn  = 2;
constexpr int Cn  = 128;
constexpr int Hn  = 96;
constexpr int Wn  = 96;
constexpr int HWn = Hn * Wn;        // 9216
constexpr int CHWn = Cn * HWn;      // 1179648
constexpr int KCn = Cn * 9;         // 1152
constexpr float EPSn = 1e-5f;
constexpr int KPAD = 1160;          // LDS row stride in shorts (2320B, 16B-aligned)

typedef short bf16x8 __attribute__((ext_vector_type(8)));
typedef float f32x4  __attribute__((ext_vector_type(4)));

static __device__ inline short f2bf(float f) {
    union { float f; unsigned u; } v; v.f = f;
    unsigned r = v.u + 0x7fff + ((v.u >> 16) & 1);
    return (short)(r >> 16);
}
// packed bf16 convert: lo = bf16(a), hi = bf16(b)  [gfx950 v_cvt_pk_bf16_f32]
static __device__ inline unsigned pack2(float a, float b) {
    unsigned r;
    asm("v_cvt_pk_bf16_f32 %0, %1, %2" : "=v"(r) : "v"(a), "v"(b));
    return r;
}

// k-major permuted weights: wb[o][k*128 + c] = w[o][c*9 + k]
__global__ __launch_bounds__(256) void cvt_w_kernel(
    const float* __restrict__ w, short* __restrict__ wb)
{
    int t = blockIdx.x * 256 + threadIdx.x;   // 128*1152
    if (t >= Cn * KCn) return;
    int o = t / KCn, r = t % KCn;
    int k = r >> 7, c = r & 127;
    wb[t] = f2bf(w[o * KCn + c * 9 + k]);
}

__global__ __launch_bounds__(256) void cvt_ow_kernel(
    const float* __restrict__ ow, short* __restrict__ owb)
{
    int t = blockIdx.x * 256 + threadIdx.x;   // 32*1152
    if (t >= 32 * KCn) return;
    int row = t / KCn, r = t % KCn;
    int k = r >> 7, c = r & 127;
    owb[t] = (row < 27) ? f2bf(ow[row * KCn + c * 9 + k]) : (short)0;
}

// NCHW -> NHWC (global-pixel-major): xT[(b*HWn+sp)*128 + c] = x[b][c][sp]
__global__ __launch_bounds__(256) void nchw2nhwc(
    const float* __restrict__ x, float* __restrict__ xT)
{
    __shared__ float Tl[128][65];
    const int t = threadIdx.x;
    const int pix0 = blockIdx.x * 64;         // 64 pixels, never crosses batch
    const int b   = pix0 / HWn;
    const int sp0 = pix0 - b * HWn;
    const float* xb = x + b * CHWn + sp0 + (t & 63);
    const int c0 = t >> 6;                    // 0..3
#pragma unroll 8
    for (int i = 0; i < 32; ++i) {
        const int c = c0 + 4 * i;
        Tl[c][t & 63] = xb[c * HWn];
    }
    __syncthreads();
    float* dst = xT + pix0 * 128;
#pragma unroll 8
    for (int i = 0; i < 32; ++i) {
        const int o = t + 256 * i;            // 0..8191
        dst[o] = Tl[o & 127][o >> 7];
    }
}

// One fused residual block, 16 pixels / 512 threads, NHWC input, k-major K.
__global__ __launch_bounds__(512, 6) void fused_stage(
    const float* __restrict__ xT, const short* __restrict__ wb,
    const short* __restrict__ owb, const float* __restrict__ obv,
    const float* __restrict__ gv, const float* __restrict__ bv,
    const float* __restrict__ mv, const float* __restrict__ vv,
    float* __restrict__ outT, float* __restrict__ outC, int dil, int last)
{
    __shared__ short S[16 * KPAD];            // im2col tile S[p][K'], 37120B
    __shared__ float offL[16][18];
    __shared__ float maskL[16][9];

    const int t   = threadIdx.x;
    const int l   = t & 63;
    const int wv  = t >> 6;                   // wave 0..7

    // XCD-aware bijective swizzle: 1152 blocks = 8 XCDs x 144 contiguous
    const int bid = blockIdx.x;
    const int swz = (bid & 7) * 144 + (bid >> 3);
    const int pix0 = swz * 16;                // never crosses a row (96%16==0)
    const int b   = pix0 / HWn;
    const int sp0 = pix0 - b * HWn;
    const int hy  = sp0 / Wn;
    const int wx0 = sp0 - hy * Wn;
    const int basep = b * HWn;

    // ---- gather-int (NHWC): wave = (pixel,tap) pair, lane = channel pair ----
    // addresses are wave-uniform -> force SGPR base via readfirstlane
#pragma unroll 9
    for (int i = 0; i < 18; ++i) {
        const int di = i / 9;                 // 0/1
        const int k  = i - di * 9;
        const int pp = wv * 2 + di;
        const int iy = hy + (k / 3 - 1) * dil;
        const int ix = wx0 + pp + (k % 3 - 1) * dil;
        const bool v = (iy >= 0) && (iy < Hn) && (ix >= 0) && (ix < Wn);
        const int aof = __builtin_amdgcn_readfirstlane(v ? (basep + iy * Wn + ix) : basep);
        const float mkf = v ? 1.f : 0.f;
        float2 val = ((const float2*)(xT + aof * 128))[l];
        ((unsigned*)&S[pp * KPAD + k * 128])[l] = pack2(val.x * mkf, val.y * mkf);
    }
    __syncthreads();

    // ---- offconv GEMM: M=32 -> 2 M-halves x 4 K-sections over 8 waves ----
    const int mh = wv & 1, ks = wv >> 1;
    f32x4 oacc = {0.f, 0.f, 0.f, 0.f};
    {
        const short* oarow = owb + (mh * 16 + (l & 15)) * KCn + ks * 288 + ((l >> 4) * 8);
        const short* srow  = &S[(l & 15) * KPAD + ks * 288 + ((l >> 4) * 8)];
#pragma unroll 9
        for (int kk = 0; kk < 9; ++kk) {
            bf16x8 af = *(const bf16x8*)(oarow + kk * 32);
            bf16x8 bf = *(const bf16x8*)(srow + kk * 32);
            oacc = __builtin_amdgcn_mfma_f32_16x16x32_bf16(af, bf, oacc, 0, 0, 0);
        }
    }
    __syncthreads();                           // S(int) reads done
    float* red = (float*)S;                    // 8 waves x 64 lanes x f32x4 = 8KB
    *(f32x4*)&red[wv * 256 + l * 4] = oacc;
    __syncthreads();
    if (wv < 2) {
        f32x4 s0 = *(const f32x4*)&red[(0 * 2 + wv) * 256 + l * 4];
        f32x4 s1 = *(const f32x4*)&red[(1 * 2 + wv) * 256 + l * 4];
        f32x4 s2 = *(const f32x4*)&red[(2 * 2 + wv) * 256 + l * 4];
        f32x4 s3 = *(const f32x4*)&red[(3 * 2 + wv) * 256 + l * 4];
        f32x4 sm = (s0 + s1) + (s2 + s3);
#pragma unroll
        for (int r = 0; r < 4; ++r) {
            int oc = wv * 16 + ((l >> 4) << 2) + r;
            if (oc < 18) {
                offL[l & 15][oc] = sm[r] + obv[oc];
            } else if (oc < 27) {
                float z = sm[r] + obv[oc];
                maskL[l & 15][oc - 18] = 1.f / (1.f + expf(-z));
            }
        }
    }
    __syncthreads();                           // offL/maskL ready

    // ---- bilinear params: lane j (<18) computes set (pp=wv*2+j/9, k=j%9) ----
    int pw0i = 0, pw1i = 0, pw2i = 0, pw3i = 0, pa0 = 0, pa1 = 0, pdx = 0;
    if (l < 18) {
        const int p = wv * 2 + l / 9;
        const int k = l - 9 * (l / 9);
        const float offy = offL[p][2 * k];
        const float offx = offL[p][2 * k + 1];
        const float m    = maskL[p][k];
        const float py = (float)(hy + (k / 3 - 1) * dil) + offy;
        const float px = (float)(wx0 + p + (k % 3 - 1) * dil) + offx;
        const float y0f = floorf(py), x0f = floorf(px);
        const float ly = py - y0f, lx = px - x0f;
        const int y0 = (int)y0f, x0 = (int)x0f;
        const float yv0 = (y0 >= 0 && y0 < Hn)      ? 1.f : 0.f;
        const float yv1 = (y0 >= -1 && y0 < Hn - 1) ? 1.f : 0.f;
        const float xv0 = (x0 >= 0 && x0 < Wn)      ? 1.f : 0.f;
        const float xv1 = (x0 >= -1 && x0 < Wn - 1) ? 1.f : 0.f;
        const float wy0 = (1.f - ly) * yv0 * m;
        const float wy1 = ly * yv1 * m;
        const float wxa = (1.f - lx) * xv0;
        const float wxb = lx * xv1;
        pw0i = __float_as_int(wy0 * wxa);
        pw1i = __float_as_int(wy0 * wxb);
        pw2i = __float_as_int(wy1 * wxa);
        pw3i = __float_as_int(wy1 * wxb);
        const int y0c = min(max(y0, 0), Hn - 1), y1c = min(max(y0 + 1, 0), Hn - 1);
        const int x0c = min(max(x0, 0), Wn - 1), x1c = min(max(x0 + 1, 0), Wn - 1);
        pa0 = (basep + y0c * Wn + x0c) * 128;
        pa1 = (basep + y1c * Wn + x1c) * 128;
        pdx = (x1c - x0c) * 128;
    }
    // no barrier: params are wave-internal

    // ---- gather-bil (NHWC): params broadcast via readlane, lane = ch pair ----
#pragma unroll 6
    for (int i = 0; i < 18; ++i) {
        const int di = i / 9;
        const int k  = i - di * 9;
        const int pp = wv * 2 + di;
        const float w00 = __int_as_float(__builtin_amdgcn_readlane(pw0i, i));
        const float w01 = __int_as_float(__builtin_amdgcn_readlane(pw1i, i));
        const float w10 = __int_as_float(__builtin_amdgcn_readlane(pw2i, i));
        const float w11 = __int_as_float(__builtin_amdgcn_readlane(pw3i, i));
        const int a00 = __builtin_amdgcn_readlane(pa0, i);
        const int a11 = __builtin_amdgcn_readlane(pa1, i);
        const int dxk = __builtin_amdgcn_readlane(pdx, i);
        const float* xp = xT + a00;
        const float* xq = xT + a11;
        float2 v00 = ((const float2*)xp)[l];
        float2 v01 = ((const float2*)(xp + dxk))[l];
        float2 v10 = ((const float2*)(xq - dxk))[l];
        float2 v11 = ((const float2*)xq)[l];
        float s0 = w00 * v00.x + w01 * v01.x + w10 * v10.x + w11 * v11.x;
        float s1 = w00 * v00.y + w01 * v01.y + w10 * v10.y + w11 * v11.y;
        ((unsigned*)&S[pp * KPAD + k * 128])[l] = pack2(s0, s1);
    }
    __syncthreads();

    // ---- dconv GEMM: wave wv -> output channels wv*16 .. wv*16+15 ----
    f32x4 dacc = {0.f, 0.f, 0.f, 0.f};
    {
        const short* darow = wb + (wv * 16 + (l & 15)) * KCn + ((l >> 4) * 8);
        const short* srow  = &S[(l & 15) * KPAD + ((l >> 4) * 8)];
#pragma unroll 4
        for (int kk = 0; kk < 36; ++kk) {
            bf16x8 af = *(const bf16x8*)(darow + kk * 32);
            bf16x8 bf = *(const bf16x8*)(srow + kk * 32);
            dacc = __builtin_amdgcn_mfma_f32_16x16x32_bf16(af, bf, dacc, 0, 0, 0);
        }
    }

    // ---- epilogue: BN + ReLU + residual ----
    const int pp  = l & 15;
    const int ocb = wv * 16 + ((l >> 4) << 2);
    if (last) {
        // NCHW out, residual from NHWC input
#pragma unroll
        for (int r = 0; r < 4; ++r) {
            const int oc = ocb + r;
            const float sc = gv[oc] * rsqrtf(vv[oc] + EPSn);
            float y = (dacc[r] - mv[oc]) * sc + bv[oc];
            y = fmaxf(y, 0.f);
            y += xT[(pix0 + pp) * 128 + oc];
            outC[b * CHWn + oc * HWn + sp0 + pp] = y;
        }
    } else {
        __syncthreads();                       // all S reads done; alias O on S
        float* O = (float*)S;                  // O[16][132]
#pragma unroll
        for (int r = 0; r < 4; ++r) {
            const int oc = ocb + r;
            const float sc = gv[oc] * rsqrtf(vv[oc] + EPSn);
            float y = (dacc[r] - mv[oc]) * sc + bv[oc];
            O[pp * 132 + oc] = fmaxf(y, 0.f);
        }
        __syncthreads();
        // coalesced NHWC write + coalesced residual read
        const int o  = t * 4;                  // 0..2047
        const int qp = o >> 7, qc = o & 127;
        f32x4 yv = *(f32x4*)&O[qp * 132 + qc];
        f32x4 rv = *(const f32x4*)&xT[(pix0 + qp) * 128 + qc];
        yv += rv;
        *(f32x4*)&outT[(pix0 + qp) * 128 + qc] = yv;
    }
}

extern "C" void kernel_launch(void* const* d_in, const int* in_sizes, int n_in,
                              void* d_out, int out_size, void* d_ws, size_t ws_size,
                              hipStream_t stream) {
    (void)in_sizes; (void)n_in; (void)out_size; (void)ws_size;

    const float* hu = (const float*)d_in[0];

    short* wb  = (short*)d_ws;                    // 3 * 147456 shorts
    short* owb = wb + 3 * Cn * KCn;               // 3 * 36864 shorts
    float* T0  = (float*)(owb + 3 * 32 * KCn);    // Bn*CHWn floats (NHWC)
    float* T1  = T0 + Bn * CHWn;                  // Bn*CHWn floats (NHWC)

    for (int i = 0; i < 3; ++i) {
        cvt_w_kernel<<<(Cn * KCn + 255) / 256, 256, 0, stream>>>(
            (const float*)d_in[3 + 7 * i], wb + i * Cn * KCn);
        cvt_ow_kernel<<<(32 * KCn + 255) / 256, 256, 0, stream>>>(
            (const float*)d_in[1 + 7 * i], owb + i * 32 * KCn);
    }

    nchw2nhwc<<<(Bn * HWn) / 64, 256, 0, stream>>>(hu, T0);

    const int dils[3] = {2, 4, 8};
    // stage1: T0 -> T1 ; stage2: T1 -> T0 ; stage3: T0 -> d_out (NCHW)
    const float* ins[3] = {T0, T1, T0};
    float*       outsT[3] = {T1, T0, nullptr};
    const int nblk = (Bn * HWn) / 16;             // 1152

    for (int i = 0; i < 3; ++i) {
        const float* obv = (const float*)d_in[2 + 7 * i];
        const float* gv  = (const float*)d_in[4 + 7 * i];
        const float* bv  = (const float*)d_in[5 + 7 * i];
        const float* mv  = (const float*)d_in[6 + 7 * i];
        const float* vv  = (const float*)d_in[7 + 7 * i];
        const int last = (i == 2);

        fused_stage<<<nblk, 512, 0, stream>>>(
            ins[i], wb + i * Cn * KCn, owb + i * 32 * KCn, obv,
            gv, bv, mv, vv, outsT[i], last ? (float*)d_out : nullptr,
            dils[i], last);
    }
}

// Round 11
// 264.309 us; speedup vs baseline: 1.0174x; 1.0174x over previous
//
#include <hip/hip_runtime.h>
#include <math.h>

constexpr int Bn  = 2;
constexpr int Cn  = 128;
constexpr int Hn  = 96;
constexpr int Wn  = 96;
constexpr int HWn = Hn * Wn;        // 9216
constexpr int CHWn = Cn * HWn;      // 1179648
constexpr int KCn = Cn * 9;         // 1152
constexpr float EPSn = 1e-5f;
constexpr int KPAD = 1160;          // LDS row stride in shorts (2320B, 16B-aligned)

typedef short bf16x8 __attribute__((ext_vector_type(8)));
typedef float f32x4  __attribute__((ext_vector_type(4)));

static __device__ inline short f2bf(float f) {
    union { float f; unsigned u; } v; v.f = f;
    unsigned r = v.u + 0x7fff + ((v.u >> 16) & 1);
    return (short)(r >> 16);
}
// packed bf16 convert: lo = bf16(a), hi = bf16(b)
static __device__ inline unsigned pack2(float a, float b) {
    unsigned r;
    asm("v_cvt_pk_bf16_f32 %0, %1, %2" : "=v"(r) : "v"(a), "v"(b));
    return r;
}

// k-major permuted weights: wb[o][k*128 + c] = w[o][c*9 + k]
__global__ __launch_bounds__(256) void cvt_w_kernel(
    const float* __restrict__ w, short* __restrict__ wb)
{
    int t = blockIdx.x * 256 + threadIdx.x;   // 128*1152
    if (t >= Cn * KCn) return;
    int o = t / KCn, r = t % KCn;
    int k = r >> 7, c = r & 127;
    wb[t] = f2bf(w[o * KCn + c * 9 + k]);
}

__global__ __launch_bounds__(256) void cvt_ow_kernel(
    const float* __restrict__ ow, short* __restrict__ owb)
{
    int t = blockIdx.x * 256 + threadIdx.x;   // 32*1152
    if (t >= 32 * KCn) return;
    int row = t / KCn, r = t % KCn;
    int k = r >> 7, c = r & 127;
    owb[t] = (row < 27) ? f2bf(ow[row * KCn + c * 9 + k]) : (short)0;
}

// NCHW -> NHWC (global-pixel-major)
__global__ __launch_bounds__(256) void nchw2nhwc(
    const float* __restrict__ x, float* __restrict__ xT)
{
    __shared__ float Tl[128][65];
    const int t = threadIdx.x;
    const int pix0 = blockIdx.x * 64;
    const int b   = pix0 / HWn;
    const int sp0 = pix0 - b * HWn;
    const float* xb = x + b * CHWn + sp0 + (t & 63);
    const int c0 = t >> 6;
#pragma unroll 8
    for (int i = 0; i < 32; ++i) {
        const int c = c0 + 4 * i;
        Tl[c][t & 63] = xb[c * HWn];
    }
    __syncthreads();
    float* dst = xT + pix0 * 128;
#pragma unroll 8
    for (int i = 0; i < 32; ++i) {
        const int o = t + 256 * i;
        dst[o] = Tl[o & 127][o >> 7];
    }
}

// One fused residual block, 16 pixels / 512 threads, NHWC, k-major K.
// All load loops are explicit batch-load / batch-consume to force MLP.
__global__ __launch_bounds__(512, 6) void fused_stage(
    const float* __restrict__ xT, const short* __restrict__ wb,
    const short* __restrict__ owb, const float* __restrict__ obv,
    const float* __restrict__ gv, const float* __restrict__ bv,
    const float* __restrict__ mv, const float* __restrict__ vv,
    float* __restrict__ outT, float* __restrict__ outC, int dil, int last)
{
    __shared__ short S[16 * KPAD];            // im2col tile S[p][K'], 37120B
    __shared__ float offL[16][18];
    __shared__ float maskL[16][9];

    const int t   = threadIdx.x;
    const int l   = t & 63;
    const int wv  = t >> 6;                   // wave 0..7

    // XCD-aware bijective swizzle: 1152 blocks = 8 XCDs x 144 contiguous
    const int bid = blockIdx.x;
    const int swz = (bid & 7) * 144 + (bid >> 3);
    const int pix0 = swz * 16;
    const int b   = pix0 / HWn;
    const int sp0 = pix0 - b * HWn;
    const int hy  = sp0 / Wn;
    const int wx0 = sp0 - hy * Wn;
    const int basep = b * HWn;

    // ---- gather-int: 3 batches x 6 loads, explicit load->consume split ----
#pragma unroll
    for (int bch = 0; bch < 3; ++bch) {
        float2 vle[6];
        float  mks[6];
#pragma unroll
        for (int u = 0; u < 6; ++u) {
            const int i  = bch * 6 + u;
            const int di = i / 9;
            const int k  = i - di * 9;
            const int pp = wv * 2 + di;
            const int iy = hy + (k / 3 - 1) * dil;
            const int ix = wx0 + pp + (k % 3 - 1) * dil;
            const bool v = (iy >= 0) && (iy < Hn) && (ix >= 0) && (ix < Wn);
            const int aof = __builtin_amdgcn_readfirstlane(v ? (basep + iy * Wn + ix) : basep);
            mks[u] = v ? 1.f : 0.f;
            vle[u] = ((const float2*)(xT + aof * 128))[l];
        }
#pragma unroll
        for (int u = 0; u < 6; ++u) {
            const int i  = bch * 6 + u;
            const int di = i / 9;
            const int k  = i - di * 9;
            const int pp = wv * 2 + di;
            ((unsigned*)&S[pp * KPAD + k * 128])[l] = pack2(vle[u].x * mks[u], vle[u].y * mks[u]);
        }
    }
    __syncthreads();

    // ---- offconv GEMM: 3 batches x 3 (A,B) frag pairs ----
    const int mh = wv & 1, ks = wv >> 1;
    f32x4 oacc = {0.f, 0.f, 0.f, 0.f};
    {
        const short* oarow = owb + (mh * 16 + (l & 15)) * KCn + ks * 288 + ((l >> 4) * 8);
        const short* srow  = &S[(l & 15) * KPAD + ks * 288 + ((l >> 4) * 8)];
#pragma unroll
        for (int bch = 0; bch < 3; ++bch) {
            bf16x8 af[3], bf[3];
#pragma unroll
            for (int u = 0; u < 3; ++u) {
                af[u] = *(const bf16x8*)(oarow + (bch * 3 + u) * 32);
                bf[u] = *(const bf16x8*)(srow  + (bch * 3 + u) * 32);
            }
#pragma unroll
            for (int u = 0; u < 3; ++u)
                oacc = __builtin_amdgcn_mfma_f32_16x16x32_bf16(af[u], bf[u], oacc, 0, 0, 0);
        }
    }
    __syncthreads();                           // S(int) reads done
    float* red = (float*)S;                    // 8 waves x 64 lanes x f32x4 = 8KB
    *(f32x4*)&red[wv * 256 + l * 4] = oacc;
    __syncthreads();
    if (wv < 2) {
        f32x4 s0 = *(const f32x4*)&red[(0 * 2 + wv) * 256 + l * 4];
        f32x4 s1 = *(const f32x4*)&red[(1 * 2 + wv) * 256 + l * 4];
        f32x4 s2 = *(const f32x4*)&red[(2 * 2 + wv) * 256 + l * 4];
        f32x4 s3 = *(const f32x4*)&red[(3 * 2 + wv) * 256 + l * 4];
        f32x4 sm = (s0 + s1) + (s2 + s3);
#pragma unroll
        for (int r = 0; r < 4; ++r) {
            int oc = wv * 16 + ((l >> 4) << 2) + r;
            if (oc < 18) {
                offL[l & 15][oc] = sm[r] + obv[oc];
            } else if (oc < 27) {
                float z = sm[r] + obv[oc];
                maskL[l & 15][oc - 18] = 1.f / (1.f + expf(-z));
            }
        }
    }
    __syncthreads();                           // offL/maskL ready

    // ---- bilinear params: lane j (<18) computes set (pp=wv*2+j/9, k=j%9) ----
    int pw0i = 0, pw1i = 0, pw2i = 0, pw3i = 0, pa0 = 0, pa1 = 0, pdx = 0;
    if (l < 18) {
        const int p = wv * 2 + l / 9;
        const int k = l - 9 * (l / 9);
        const float offy = offL[p][2 * k];
        const float offx = offL[p][2 * k + 1];
        const float m    = maskL[p][k];
        const float py = (float)(hy + (k / 3 - 1) * dil) + offy;
        const float px = (float)(wx0 + p + (k % 3 - 1) * dil) + offx;
        const float y0f = floorf(py), x0f = floorf(px);
        const float ly = py - y0f, lx = px - x0f;
        const int y0 = (int)y0f, x0 = (int)x0f;
        const float yv0 = (y0 >= 0 && y0 < Hn)      ? 1.f : 0.f;
        const float yv1 = (y0 >= -1 && y0 < Hn - 1) ? 1.f : 0.f;
        const float xv0 = (x0 >= 0 && x0 < Wn)      ? 1.f : 0.f;
        const float xv1 = (x0 >= -1 && x0 < Wn - 1) ? 1.f : 0.f;
        const float wy0 = (1.f - ly) * yv0 * m;
        const float wy1 = ly * yv1 * m;
        const float wxa = (1.f - lx) * xv0;
        const float wxb = lx * xv1;
        pw0i = __float_as_int(wy0 * wxa);
        pw1i = __float_as_int(wy0 * wxb);
        pw2i = __float_as_int(wy1 * wxa);
        pw3i = __float_as_int(wy1 * wxb);
        const int y0c = min(max(y0, 0), Hn - 1), y1c = min(max(y0 + 1, 0), Hn - 1);
        const int x0c = min(max(x0, 0), Wn - 1), x1c = min(max(x0 + 1, 0), Wn - 1);
        pa0 = (basep + y0c * Wn + x0c) * 128;
        pa1 = (basep + y1c * Wn + x1c) * 128;
        pdx = (x1c - x0c) * 128;
    }

    // ---- gather-bil: 6 batches x 3 taps x 4 loads (12 float2 in flight) ----
#pragma unroll
    for (int bch = 0; bch < 6; ++bch) {
        float2 v00[3], v01[3], v10[3], v11[3];
        float  w00[3], w01[3], w10[3], w11[3];
#pragma unroll
        for (int u = 0; u < 3; ++u) {
            const int i = bch * 3 + u;
            w00[u] = __int_as_float(__builtin_amdgcn_readlane(pw0i, i));
            w01[u] = __int_as_float(__builtin_amdgcn_readlane(pw1i, i));
            w10[u] = __int_as_float(__builtin_amdgcn_readlane(pw2i, i));
            w11[u] = __int_as_float(__builtin_amdgcn_readlane(pw3i, i));
            const int a00 = __builtin_amdgcn_readlane(pa0, i);
            const int a11 = __builtin_amdgcn_readlane(pa1, i);
            const int dxk = __builtin_amdgcn_readlane(pdx, i);
            const float* xp = xT + a00;
            const float* xq = xT + a11;
            v00[u] = ((const float2*)xp)[l];
            v01[u] = ((const float2*)(xp + dxk))[l];
            v10[u] = ((const float2*)(xq - dxk))[l];
            v11[u] = ((const float2*)xq)[l];
        }
#pragma unroll
        for (int u = 0; u < 3; ++u) {
            const int i  = bch * 3 + u;
            const int di = i / 9;
            const int k  = i - di * 9;
            const int pp = wv * 2 + di;
            float s0 = w00[u] * v00[u].x + w01[u] * v01[u].x + w10[u] * v10[u].x + w11[u] * v11[u].x;
            float s1 = w00[u] * v00[u].y + w01[u] * v01[u].y + w10[u] * v10[u].y + w11[u] * v11[u].y;
            ((unsigned*)&S[pp * KPAD + k * 128])[l] = pack2(s0, s1);
        }
    }
    __syncthreads();

    // ---- dconv GEMM: 6 batches x 6 (A,B) frag pairs ----
    f32x4 dacc = {0.f, 0.f, 0.f, 0.f};
    {
        const short* darow = wb + (wv * 16 + (l & 15)) * KCn + ((l >> 4) * 8);
        const short* srow  = &S[(l & 15) * KPAD + ((l >> 4) * 8)];
#pragma unroll
        for (int bch = 0; bch < 6; ++bch) {
            bf16x8 af[6], bf[6];
#pragma unroll
            for (int u = 0; u < 6; ++u) {
                af[u] = *(const bf16x8*)(darow + (bch * 6 + u) * 32);
                bf[u] = *(const bf16x8*)(srow  + (bch * 6 + u) * 32);
            }
#pragma unroll
            for (int u = 0; u < 6; ++u)
                dacc = __builtin_amdgcn_mfma_f32_16x16x32_bf16(af[u], bf[u], dacc, 0, 0, 0);
        }
    }

    // ---- epilogue: BN + ReLU + residual ----
    const int pp  = l & 15;
    const int ocb = wv * 16 + ((l >> 4) << 2);
    if (last) {
#pragma unroll
        for (int r = 0; r < 4; ++r) {
            const int oc = ocb + r;
            const float sc = gv[oc] * rsqrtf(vv[oc] + EPSn);
            float y = (dacc[r] - mv[oc]) * sc + bv[oc];
            y = fmaxf(y, 0.f);
            y += xT[(pix0 + pp) * 128 + oc];
            outC[b * CHWn + oc * HWn + sp0 + pp] = y;
        }
    } else {
        __syncthreads();                       // all S reads done; alias O on S
        float* O = (float*)S;                  // O[16][132]
#pragma unroll
        for (int r = 0; r < 4; ++r) {
            const int oc = ocb + r;
            const float sc = gv[oc] * rsqrtf(vv[oc] + EPSn);
            float y = (dacc[r] - mv[oc]) * sc + bv[oc];
            O[pp * 132 + oc] = fmaxf(y, 0.f);
        }
        __syncthreads();
        const int o  = t * 4;                  // 0..2047
        const int qp = o >> 7, qc = o & 127;
        f32x4 yv = *(f32x4*)&O[qp * 132 + qc];
        f32x4 rv = *(const f32x4*)&xT[(pix0 + qp) * 128 + qc];
        yv += rv;
        *(f32x4*)&outT[(pix0 + qp) * 128 + qc] = yv;
    }
}

extern "C" void kernel_launch(void* const* d_in, const int* in_sizes, int n_in,
                              void* d_out, int out_size, void* d_ws, size_t ws_size,
                              hipStream_t stream) {
    (void)in_sizes; (void)n_in; (void)out_size; (void)ws_size;

    const float* hu = (const float*)d_in[0];

    short* wb  = (short*)d_ws;                    // 3 * 147456 shorts
    short* owb = wb + 3 * Cn * KCn;               // 3 * 36864 shorts
    float* T0  = (float*)(owb + 3 * 32 * KCn);    // Bn*CHWn floats (NHWC)
    float* T1  = T0 + Bn * CHWn;                  // Bn*CHWn floats (NHWC)

    for (int i = 0; i < 3; ++i) {
        cvt_w_kernel<<<(Cn * KCn + 255) / 256, 256, 0, stream>>>(
            (const float*)d_in[3 + 7 * i], wb + i * Cn * KCn);
        cvt_ow_kernel<<<(32 * KCn + 255) / 256, 256, 0, stream>>>(
            (const float*)d_in[1 + 7 * i], owb + i * 32 * KCn);
    }

    nchw2nhwc<<<(Bn * HWn) / 64, 256, 0, stream>>>(hu, T0);

    const int dils[3] = {2, 4, 8};
    const float* ins[3] = {T0, T1, T0};
    float*       outsT[3] = {T1, T0, nullptr};
    const int nblk = (Bn * HWn) / 16;             // 1152

    for (int i = 0; i < 3; ++i) {
        const float* obv = (const float*)d_in[2 + 7 * i];
        const float* gv  = (const float*)d_in[4 + 7 * i];
        const float* bv  = (const float*)d_in[5 + 7 * i];
        const float* mv  = (const float*)d_in[6 + 7 * i];
        const float* vv  = (const float*)d_in[7 + 7 * i];
        const int last = (i == 2);

        fused_stage<<<nblk, 512, 0, stream>>>(
            ins[i], wb + i * Cn * KCn, owb + i * 32 * KCn, obv,
            gv, bv, mv, vv, outsT[i], last ? (float*)d_out : nullptr,
            dils[i], last);
    }
}